// Round 11
// baseline (397.205 us; speedup 1.0000x reference)
//
#include <hip/hip_runtime.h>
#include <hip/hip_bf16.h>
#include <math.h>

// Problem constants
constexpr int NN = 100000;   // nodes
constexpr int EE = 1600000;  // edges
constexpr int GG = 512;      // graphs
constexpr int MPAD = 100096; // 782 * 128 row-padded M
constexpr int NBUCK = 782;   // MPAD / 128 coarse buckets (128 nodes each)
constexpr int EPB = 4096;    // edges per partition block (8 per thread)
constexpr int CAP = 4096;    // per-bucket fixed capacity (mean 2048, sigma~45)
constexpr int GB1 = MPAD / 128;             // 782 gemm blocks
constexpr int PBLK = (EE + EPB - 1) / EPB;  // 391 partition blocks

typedef __attribute__((ext_vector_type(8))) short short8;
typedef __attribute__((ext_vector_type(4))) float floatx4;

__device__ __forceinline__ unsigned short f2bf_rne(float f) {
    unsigned int u = __float_as_uint(f);
    u += 0x7fff + ((u >> 16) & 1);
    return (unsigned short)(u >> 16);
}
__device__ __forceinline__ float bf_lo(unsigned int u) { return __uint_as_float(u << 16); }
__device__ __forceinline__ float bf_hi(unsigned int u) { return __uint_as_float(u & 0xffff0000u); }

// DPP-based add: single v_add_f32 with DPP ctrl on src.
template<int C>
__device__ __forceinline__ float dppadd(float x) {
    int t = __builtin_amdgcn_update_dpp(0, __float_as_int(x), C, 0xf, 0xf, true);
    return x + __int_as_float(t);
}

// 8-feature dot: lane's uint4 of bf16 pairs vs pre-scaled q[8].
__device__ __forceinline__ float dot8(uint4 kd, const float* q) {
    float p =      bf_lo(kd.x) * q[0];
    p = fmaf(bf_hi(kd.x), q[1], p);
    p = fmaf(bf_lo(kd.y), q[2], p);
    p = fmaf(bf_hi(kd.y), q[3], p);
    p = fmaf(bf_lo(kd.z), q[4], p);
    p = fmaf(bf_hi(kd.z), q[5], p);
    p = fmaf(bf_lo(kd.w), q[6], p);
    p = fmaf(bf_hi(kd.w), q[7], p);
    return p;
}
__device__ __forceinline__ void acc8(float* a, float e, uint4 vd) {
    a[0] = fmaf(e, bf_lo(vd.x), a[0]);
    a[1] = fmaf(e, bf_hi(vd.x), a[1]);
    a[2] = fmaf(e, bf_lo(vd.y), a[2]);
    a[3] = fmaf(e, bf_hi(vd.y), a[3]);
    a[4] = fmaf(e, bf_lo(vd.z), a[4]);
    a[5] = fmaf(e, bf_hi(vd.z), a[5]);
    a[6] = fmaf(e, bf_lo(vd.w), a[6]);
    a[7] = fmaf(e, bf_hi(vd.w), a[7]);
}

// ---------------------------------------------------------------------------
// Partition body: fixed-stride bucket partition (8 edges/thread).
// ---------------------------------------------------------------------------
__device__ void part_body(int bb, const int* __restrict__ src,
                          const int* __restrict__ dst,
                          int* __restrict__ bcur,
                          unsigned int* __restrict__ ppair,
                          char* smem) {
    int* cnt  = reinterpret_cast<int*>(smem);
    int* base = cnt + NBUCK;
    int tid = threadIdx.x;
    int e0 = bb * EPB;
    for (int j = tid; j < NBUCK; j += 512) cnt[j] = 0;
    __syncthreads();
    int myd[8], myr[8];
    #pragma unroll
    for (int t = 0; t < 8; t++) {
        int i = e0 + t * 512 + tid;
        if (i < EE) {
            int d = dst[i];
            myd[t] = d;
            myr[t] = atomicAdd(&cnt[d >> 7], 1);
        } else myd[t] = -1;
    }
    __syncthreads();
    for (int j = tid; j < NBUCK; j += 512) base[j] = atomicAdd(&bcur[j], cnt[j]);
    __syncthreads();
    #pragma unroll
    for (int t = 0; t < 8; t++) {
        int i = e0 + t * 512 + tid;
        if (myd[t] >= 0) {
            int b = myd[t] >> 7;
            int pos = base[b] + myr[t];
            if (pos < CAP)
                ppair[(size_t)b * CAP + pos] =
                    ((unsigned int)src[i] << 7) | (unsigned int)(myd[t] & 127);
        }
    }
}

// ---------------------------------------------------------------------------
// GEMM body: A[M][K] @ Bt[256][K] -> kv [k|v] bf16 + qsb [q|s] bf16.
// Block = 128 rows x 256 cols, 512 threads (8 waves, 2x4). A read ONCE.
// ---------------------------------------------------------------------------
template<int K, bool AF32>
__device__ void gemm_body(int bb, const void* __restrict__ Araw,
                          const unsigned short* __restrict__ Bt,
                          const float* __restrict__ bias,
                          unsigned short* __restrict__ out0,
                          unsigned short* __restrict__ out1,
                          char* smem) {
    constexpr int SP = 72;                    // 64 + 8 pad (bf16 elts)
    short* As = reinterpret_cast<short*>(smem);            // 18432 B
    short* Bs = reinterpret_cast<short*>(smem + 18432);    // 36864 B
    int tid = threadIdx.x;
    int wave = tid >> 6, lane = tid & 63;
    int wm = wave >> 2, wn = wave & 3;        // 2 row-halves x 4 col-quarters
    int quad = lane >> 4, l16 = lane & 15;
    int rowBase = bb * 128;

    floatx4 acc[4][4];
    #pragma unroll
    for (int i = 0; i < 4; i++)
        #pragma unroll
        for (int j = 0; j < 4; j++) acc[i][j] = (floatx4)0.f;

    for (int kc = 0; kc < K; kc += 64) {
        #pragma unroll
        for (int it = 0; it < 2; it++) {
            int flat = it * 512 + tid;
            int r = flat >> 3, c8 = (flat & 7) * 8;
            int ar = rowBase + r; if (ar >= NN) ar = NN - 1;   // clamp: no OOB
            short8 va;
            if constexpr (AF32) {
                const float* ap = (const float*)Araw + (size_t)ar * K + kc + c8;
                float4 u0 = *reinterpret_cast<const float4*>(ap);
                float4 u1 = *reinterpret_cast<const float4*>(ap + 4);
                va[0] = (short)f2bf_rne(u0.x); va[1] = (short)f2bf_rne(u0.y);
                va[2] = (short)f2bf_rne(u0.z); va[3] = (short)f2bf_rne(u0.w);
                va[4] = (short)f2bf_rne(u1.x); va[5] = (short)f2bf_rne(u1.y);
                va[6] = (short)f2bf_rne(u1.z); va[7] = (short)f2bf_rne(u1.w);
            } else {
                va = *reinterpret_cast<const short8*>(
                        (const unsigned short*)Araw + (size_t)ar * K + kc + c8);
            }
            *reinterpret_cast<short8*>(&As[r * SP + c8]) = va;
        }
        #pragma unroll
        for (int it = 0; it < 4; it++) {
            int flat = it * 512 + tid;
            int r = flat >> 3, c8 = (flat & 7) * 8;
            short8 vb = *reinterpret_cast<const short8*>(Bt + (size_t)r * K + kc + c8);
            *reinterpret_cast<short8*>(&Bs[r * SP + c8]) = vb;
        }
        __syncthreads();
        #pragma unroll
        for (int ks = 0; ks < 2; ks++) {
            short8 af[4], bf[4];
            #pragma unroll
            for (int i = 0; i < 4; i++)
                af[i] = *reinterpret_cast<const short8*>(&As[(wm * 64 + i * 16 + l16) * SP + ks * 32 + quad * 8]);
            #pragma unroll
            for (int j = 0; j < 4; j++)
                bf[j] = *reinterpret_cast<const short8*>(&Bs[(wn * 64 + j * 16 + l16) * SP + ks * 32 + quad * 8]);
            #pragma unroll
            for (int i = 0; i < 4; i++)
                #pragma unroll
                for (int j = 0; j < 4; j++)
                    acc[i][j] = __builtin_amdgcn_mfma_f32_16x16x32_bf16(af[i], bf[j], acc[i][j], 0, 0, 0);
        }
        __syncthreads();
    }

    unsigned short* outp = (wn < 2) ? out0 : out1;
    int colBase = (wn & 1) * 64;
    float bj[4];
    #pragma unroll
    for (int j = 0; j < 4; j++) bj[j] = bias[wn * 64 + j * 16 + l16];
    #pragma unroll
    for (int i = 0; i < 4; i++) {
        #pragma unroll
        for (int j = 0; j < 4; j++) {
            int col = colBase + j * 16 + l16;
            #pragma unroll
            for (int r = 0; r < 4; r++) {
                int row = rowBase + wm * 64 + i * 16 + quad * 4 + r;
                if (row < NN)
                    outp[(size_t)row * 128 + col] = f2bf_rne(acc[i][j][r] + bj[j]);
            }
        }
    }
}

// ---------------------------------------------------------------------------
// Fat kernel: partition blocks first (short job starts immediately), then
// conv1 gemm blocks. Independent work — overlapped in one dispatch.
// ---------------------------------------------------------------------------
__global__ __launch_bounds__(512) void k_gemm1_part(
    const float* __restrict__ x,
    const unsigned short* __restrict__ Bt,
    const float* __restrict__ bias,
    unsigned short* __restrict__ out0,
    unsigned short* __restrict__ out1,
    const int* __restrict__ src,
    const int* __restrict__ dst,
    int* __restrict__ bcur,
    unsigned int* __restrict__ ppair) {
    __shared__ __align__(16) char smem[55296];
    if (blockIdx.x < PBLK)
        part_body(blockIdx.x, src, dst, bcur, ppair, smem);
    else
        gemm_body<128, true>(blockIdx.x - PBLK, x, Bt, bias, out0, out1, smem);
}

// Standalone gemm for conv2.
__global__ __launch_bounds__(512) void k_gemm2(
    const unsigned short* __restrict__ A,
    const unsigned short* __restrict__ Bt,
    const float* __restrict__ bias,
    unsigned short* __restrict__ out0,
    unsigned short* __restrict__ out1) {
    __shared__ __align__(16) char smem[55296];
    gemm_body<64, false>(blockIdx.x, A, Bt, bias, out0, out1, smem);
}

// ---------------------------------------------------------------------------
// One block per bucket (512 threads): counting sort by exact dst.
// ---------------------------------------------------------------------------
__global__ __launch_bounds__(512) void k_bucket(const unsigned int* __restrict__ ppair,
                                                const int* __restrict__ bcur,
                                                int* __restrict__ rowbeg,
                                                int* __restrict__ rowend,
                                                int* __restrict__ csr) {
    __shared__ int cnt[128];
    __shared__ int sa[128], sb[128];
    __shared__ int cur[128];
    int t = threadIdx.x;
    int b = blockIdx.x;
    int n = bcur[b]; if (n > CAP) n = CAP;
    int start = b * CAP;
    if (t < 128) cnt[t] = 0;
    __syncthreads();
    for (int i = t; i < n; i += 512)
        atomicAdd(&cnt[ppair[start + i] & 127], 1);
    __syncthreads();
    if (t < 128) sa[t] = cnt[t];
    __syncthreads();
    int* p = sa; int* q = sb;
    for (int off = 1; off < 128; off <<= 1) {
        if (t < 128) q[t] = (t >= off) ? (p[t] + p[t - off]) : p[t];
        __syncthreads();
        int* tmp = p; p = q; q = tmp;
    }
    if (t < 128) {
        int excl = (t == 0) ? 0 : p[t - 1];
        rowbeg[b * 128 + t] = start + excl;
        rowend[b * 128 + t] = start + p[t];
        cur[t] = start + excl;
    }
    __syncthreads();
    for (int i = t; i < n; i += 512) {
        unsigned int e = ppair[start + i];
        int pos = atomicAdd(&cur[e & 127], 1);
        csr[pos] = (int)(e >> 7);
    }
}

// ---------------------------------------------------------------------------
// Pack weights for BOTH layers + zero g0 + zero bcur + BN scale/shift.
// ---------------------------------------------------------------------------
__global__ __launch_bounds__(256) void k_cvt_all(
    const float* __restrict__ w1q, const float* __restrict__ b1q,
    const float* __restrict__ w1k, const float* __restrict__ b1k,
    const float* __restrict__ w1v, const float* __restrict__ b1v,
    const float* __restrict__ w1s, const float* __restrict__ b1s,
    const float* __restrict__ w2q, const float* __restrict__ b2q,
    const float* __restrict__ w2k, const float* __restrict__ b2k,
    const float* __restrict__ w2v, const float* __restrict__ b2v,
    const float* __restrict__ w2s, const float* __restrict__ b2s,
    const float* __restrict__ bn1g, const float* __restrict__ bn1b,
    const float* __restrict__ bn1m, const float* __restrict__ bn1v,
    const float* __restrict__ bn2g, const float* __restrict__ bn2b,
    const float* __restrict__ bn2m, const float* __restrict__ bn2v,
    unsigned short* __restrict__ Bt1, float* __restrict__ bias1,
    unsigned short* __restrict__ Bt2, float* __restrict__ bias2,
    float* __restrict__ bnp, float* __restrict__ g0,
    int* __restrict__ bcur) {
    int b = blockIdx.x, tid = threadIdx.x;
    if (b < 4) {
        int z = b * 256 + tid;
        if (z < NBUCK) bcur[z] = 0;
    }
    if (b == 0 && tid < 128) {
        int layer = tid >> 6, f = tid & 63;
        float gg = layer ? bn2g[f] : bn1g[f];
        float bb = layer ? bn2b[f] : bn1b[f];
        float mm = layer ? bn2m[f] : bn1m[f];
        float vv = layer ? bn2v[f] : bn1v[f];
        float sc = gg * rsqrtf(vv + 1e-5f);
        bnp[layer * 128 + f] = sc;
        bnp[layer * 128 + 64 + f] = bb - mm * sc;
    }
    if (b < 128) {
        g0[b * 256 + tid] = 0.f;   // 128*256 = 32768 = GG*64
        int idx = b * 256 + tid;
        int col = idx >> 7, k = idx & 127;
        float val;
        if (col < 64)        val = w1k[k * 64 + col];
        else if (col < 128)  val = w1v[k * 64 + (col - 64)];
        else if (col < 192)  val = w1q[k * 64 + (col - 128)];
        else                 val = w1s[k * 64 + (col - 192)];
        Bt1[col * 128 + k] = f2bf_rne(val);
        if (k == 0) {
            float bv;
            if (col < 64)        bv = b1k[col];
            else if (col < 128)  bv = b1v[col - 64];
            else if (col < 192)  bv = b1q[col - 128];
            else                 bv = b1s[col - 192];
            bias1[col] = bv;
        }
    } else {
        int idx = (b - 128) * 256 + tid;
        int col = idx >> 6, k = idx & 63;
        float val;
        if (col < 64)        val = w2k[k * 64 + col];
        else if (col < 128)  val = w2v[k * 64 + (col - 64)];
        else if (col < 192)  val = w2q[k * 64 + (col - 128)];
        else                 val = w2s[k * 64 + (col - 192)];
        Bt2[col * 64 + k] = f2bf_rne(val);
        if (k == 0) {
            float bv;
            if (col < 64)        bv = b2k[col];
            else if (col < 128)  bv = b2v[col - 64];
            else if (col < 192)  bv = b2q[col - 128];
            else                 bv = b2s[col - 192];
            bias2[col] = bv;
        }
    }
}

// ---------------------------------------------------------------------------
// Fused attention, eighth-wave edges (unchanged from round 10).
// ---------------------------------------------------------------------------
__global__ __launch_bounds__(256) void attn_fused(
    const unsigned short* __restrict__ qsb,
    const unsigned char* __restrict__ kvb,   // 256 B per node
    const int* __restrict__ rowbeg,
    const int* __restrict__ rowend,
    const int* __restrict__ csr,
    const float* __restrict__ bnscale, const float* __restrict__ bnshift,
    uint4* __restrict__ h_out) {
    int wid = (blockIdx.x * 256 + threadIdx.x) >> 6;
    int lane = threadIdx.x & 63;
    if (wid >= NN) return;
    int g = lane >> 3, l8 = lane & 7;
    unsigned int qb16 = (unsigned int)(l8 << 4);
    const uint4* qrow = reinterpret_cast<const uint4*>(qsb + (size_t)wid * 128);
    const float SC = 0.3606737602222409f;   // 0.25 * log2(e)
    uint4 qd = qrow[l8];
    float q[8];
    q[0] = bf_lo(qd.x) * SC; q[1] = bf_hi(qd.x) * SC;
    q[2] = bf_lo(qd.y) * SC; q[3] = bf_hi(qd.y) * SC;
    q[4] = bf_lo(qd.z) * SC; q[5] = bf_hi(qd.z) * SC;
    q[6] = bf_lo(qd.w) * SC; q[7] = bf_hi(qd.w) * SC;
    int jb = rowbeg[wid], je = rowend[wid];
    float a[8] = {0.f, 0.f, 0.f, 0.f, 0.f, 0.f, 0.f, 0.f};
    float denom = 0.f;
    int j = jb;
    for (; j + 15 < je; j += 16) {
        unsigned int oA = ((unsigned int)csr[j + g] << 8) + qb16;
        unsigned int oB = ((unsigned int)csr[j + 8 + g] << 8) + qb16;
        uint4 kA = *reinterpret_cast<const uint4*>(kvb + oA);
        uint4 vA = *reinterpret_cast<const uint4*>(kvb + oA + 128);
        uint4 kB = *reinterpret_cast<const uint4*>(kvb + oB);
        uint4 vB = *reinterpret_cast<const uint4*>(kvb + oB + 128);
        float pA = dppadd<0xB1>(dot8(kA, q));
        float pB = dppadd<0xB1>(dot8(kB, q));
        float eA = exp2f(pA), eB = exp2f(pB);
        denom += eA + eB;
        acc8(a, eA, vA);
        acc8(a, eB, vB);
    }
    for (; j < je; j += 8) {
        int jj = j + g;
        bool valid = jj < je;
        unsigned int o = ((unsigned int)csr[valid ? jj : je - 1] << 8) + qb16;
        uint4 kd = *reinterpret_cast<const uint4*>(kvb + o);
        uint4 vd = *reinterpret_cast<const uint4*>(kvb + o + 128);
        float p = dppadd<0xB1>(dot8(kd, q));
        float e = valid ? exp2f(p) : 0.f;
        denom += e;
        acc8(a, e, vd);
    }
    #pragma unroll
    for (int i = 0; i < 8; i++) {
        a[i] += __shfl_xor(a[i], 8);
        a[i] += __shfl_xor(a[i], 16);
        a[i] += __shfl_xor(a[i], 32);
    }
    denom += __shfl_xor(denom, 8);
    denom += __shfl_xor(denom, 16);
    denom += __shfl_xor(denom, 32);
    float inv = 1.f / (denom + 1e-16f);
    uint4 sd = qrow[8 + l8];
    float s[8];
    s[0] = bf_lo(sd.x); s[1] = bf_hi(sd.x);
    s[2] = bf_lo(sd.y); s[3] = bf_hi(sd.y);
    s[4] = bf_lo(sd.z); s[5] = bf_hi(sd.z);
    s[6] = bf_lo(sd.w); s[7] = bf_hi(sd.w);
    const float4* scp = reinterpret_cast<const float4*>(bnscale);
    const float4* shp = reinterpret_cast<const float4*>(bnshift);
    float4 sc0 = scp[l8 * 2], sc1 = scp[l8 * 2 + 1];
    float4 sh0 = shp[l8 * 2], sh1 = shp[l8 * 2 + 1];
    float o0 = fmaxf(fmaf(a[0] * inv + s[0], sc0.x, sh0.x), 0.f);
    float o1 = fmaxf(fmaf(a[1] * inv + s[1], sc0.y, sh0.y), 0.f);
    float o2 = fmaxf(fmaf(a[2] * inv + s[2], sc0.z, sh0.z), 0.f);
    float o3 = fmaxf(fmaf(a[3] * inv + s[3], sc0.w, sh0.w), 0.f);
    float o4 = fmaxf(fmaf(a[4] * inv + s[4], sc1.x, sh1.x), 0.f);
    float o5 = fmaxf(fmaf(a[5] * inv + s[5], sc1.y, sh1.y), 0.f);
    float o6 = fmaxf(fmaf(a[6] * inv + s[6], sc1.z, sh1.z), 0.f);
    float o7 = fmaxf(fmaf(a[7] * inv + s[7], sc1.w, sh1.w), 0.f);
    if (g == 0) {
        uint4 hw;
        hw.x = (unsigned int)f2bf_rne(o0) | ((unsigned int)f2bf_rne(o1) << 16);
        hw.y = (unsigned int)f2bf_rne(o2) | ((unsigned int)f2bf_rne(o3) << 16);
        hw.z = (unsigned int)f2bf_rne(o4) | ((unsigned int)f2bf_rne(o5) << 16);
        hw.w = (unsigned int)f2bf_rne(o6) | ((unsigned int)f2bf_rne(o7) << 16);
        h_out[(size_t)wid * 8 + l8] = hw;
    }
}

// ---------------------------------------------------------------------------
// Global max pool, vectorized: lane covers 2 features (one uint). h bf16.
// ---------------------------------------------------------------------------
__global__ __launch_bounds__(256) void k_pool(const unsigned int* __restrict__ h2,
                                              const int* __restrict__ batch,
                                              float* __restrict__ g0) {
    int u = threadIdx.x & 31;          // uint index = features (2u, 2u+1)
    int sub = threadIdx.x >> 5;        // 8 sub-groups
    int n0 = blockIdx.x * 256;
    int nEnd = n0 + 256; if (nEnd > NN) nEnd = NN;
    int cur_g = -1; float m0 = 0.f, m1 = 0.f;
    for (int n = n0 + sub; n < nEnd; n += 8) {
        int bg = batch[n];
        unsigned int hv = h2[(size_t)n * 32 + u];
        float v0 = bf_lo(hv), v1 = bf_hi(hv);
        if (bg != cur_g) {
            if (cur_g >= 0) {
                atomicMax((int*)&g0[cur_g * 64 + 2 * u], __float_as_int(m0));
                atomicMax((int*)&g0[cur_g * 64 + 2 * u + 1], __float_as_int(m1));
            }
            cur_g = bg; m0 = v0; m1 = v1;
        } else {
            m0 = fmaxf(m0, v0); m1 = fmaxf(m1, v1);
        }
    }
    if (cur_g >= 0) {
        atomicMax((int*)&g0[cur_g * 64 + 2 * u], __float_as_int(m0));
        atomicMax((int*)&g0[cur_g * 64 + 2 * u + 1], __float_as_int(m1));
    }
}

// ---------------------------------------------------------------------------
// Fused MLP head: 4 layers + BN + log_softmax. One wave per graph row.
// ---------------------------------------------------------------------------
__global__ __launch_bounds__(256) void k_mlp(
    const float* __restrict__ g0,
    const float* __restrict__ p1w, const float* __restrict__ p1b,
    const float* __restrict__ p2w, const float* __restrict__ p2b,
    const float* __restrict__ cl1w, const float* __restrict__ cl1b,
    const float* __restrict__ bg, const float* __restrict__ bb,
    const float* __restrict__ bm, const float* __restrict__ bv,
    const float* __restrict__ cl2w, const float* __restrict__ cl2b,
    float* __restrict__ outp) {
    __shared__ float w1[64 * 64], w2[64 * 64], w3[64 * 64], w4[64 * 10];
    __shared__ float sb1[64], sb2[64], sb3[64], sbn[4 * 64], sb4[10];
    int tid = threadIdx.x;
    for (int i = tid; i < 64 * 64; i += 256) { w1[i] = p1w[i]; w2[i] = p2w[i]; w3[i] = cl1w[i]; }
    for (int i = tid; i < 64 * 10; i += 256) w4[i] = cl2w[i];
    if (tid < 64) {
        sb1[tid] = p1b[tid]; sb2[tid] = p2b[tid]; sb3[tid] = cl1b[tid];
        sbn[tid] = bg[tid]; sbn[64 + tid] = bb[tid];
        sbn[128 + tid] = bm[tid]; sbn[192 + tid] = bv[tid];
    }
    if (tid < 10) sb4[tid] = cl2b[tid];
    __syncthreads();
    int lane = tid & 63, w = tid >> 6;
    int row = blockIdx.x * 4 + w;
    float x = g0[row * 64 + lane];
    if (!isfinite(x)) x = 0.f;
    float a = sb1[lane];
    for (int k = 0; k < 64; k++) a += __shfl(x, k) * w1[k * 64 + lane];
    x = fmaxf(a, 0.f);
    a = sb2[lane];
    for (int k = 0; k < 64; k++) a += __shfl(x, k) * w2[k * 64 + lane];
    x = a;
    a = sb3[lane];
    for (int k = 0; k < 64; k++) a += __shfl(x, k) * w3[k * 64 + lane];
    a = (a - sbn[128 + lane]) * rsqrtf(sbn[192 + lane] + 1e-5f) * sbn[lane] + sbn[64 + lane];
    x = fmaxf(a, 0.f);
    float lg[10];
    #pragma unroll
    for (int c = 0; c < 10; c++) {
        float p = x * w4[lane * 10 + c];
        p += __shfl_xor(p, 1);  p += __shfl_xor(p, 2);  p += __shfl_xor(p, 4);
        p += __shfl_xor(p, 8);  p += __shfl_xor(p, 16); p += __shfl_xor(p, 32);
        lg[c] = p + sb4[c];
    }
    float mx = lg[0];
    #pragma unroll
    for (int c = 1; c < 10; c++) mx = fmaxf(mx, lg[c]);
    float s = 0.f;
    #pragma unroll
    for (int c = 0; c < 10; c++) s += __expf(lg[c] - mx);
    float lse = mx + logf(s);
    float o = 0.f;
    #pragma unroll
    for (int c = 0; c < 10; c++) if (lane == c) o = lg[c];
    if (lane < 10) outp[row * 10 + lane] = o - lse;
}

// ---------------------------------------------------------------------------
extern "C" void kernel_launch(void* const* d_in, const int* in_sizes, int n_in,
                              void* d_out, int out_size, void* d_ws, size_t ws_size,
                              hipStream_t stream) {
    const float* x     = (const float*)d_in[0];
    const int*   ei    = (const int*)d_in[1];
    const int*   batch = (const int*)d_in[2];
    const float *c1_wq = (const float*)d_in[3],  *c1_bq = (const float*)d_in[4];
    const float *c1_wk = (const float*)d_in[5],  *c1_bk = (const float*)d_in[6];
    const float *c1_wv = (const float*)d_in[7],  *c1_bv = (const float*)d_in[8];
    const float *c1_ws = (const float*)d_in[9],  *c1_bs = (const float*)d_in[10];
    const float *c2_wq = (const float*)d_in[11], *c2_bq = (const float*)d_in[12];
    const float *c2_wk = (const float*)d_in[13], *c2_bk = (const float*)d_in[14];
    const float *c2_wv = (const float*)d_in[15], *c2_bv = (const float*)d_in[16];
    const float *c2_ws = (const float*)d_in[17], *c2_bs = (const float*)d_in[18];
    const float *bn1_g = (const float*)d_in[19], *bn1_b = (const float*)d_in[20];
    const float *bn1_m = (const float*)d_in[21], *bn1_v = (const float*)d_in[22];
    const float *bn2_g = (const float*)d_in[23], *bn2_b = (const float*)d_in[24];
    const float *bn2_m = (const float*)d_in[25], *bn2_v = (const float*)d_in[26];
    const float *clbn_g = (const float*)d_in[27], *clbn_b = (const float*)d_in[28];
    const float *clbn_m = (const float*)d_in[29], *clbn_v = (const float*)d_in[30];
    const float *p1_w = (const float*)d_in[31], *p2_w = (const float*)d_in[32];
    const float *cl1_w = (const float*)d_in[33], *cl2_w = (const float*)d_in[34];
    const float *p1_b = (const float*)d_in[35], *p2_b = (const float*)d_in[36];
    const float *cl1_b = (const float*)d_in[37], *cl2_b = (const float*)d_in[38];

    char* ws = (char*)d_ws;
    unsigned short* kv     = (unsigned short*)(ws);               //  25,600,000
    unsigned short* qsb    = (unsigned short*)(ws + 25600000);    //  25,600,000
    unsigned short* hbuf   = (unsigned short*)(ws + 51200000);    //  12,812,288
    unsigned int*   ppair  = (unsigned int*)(ws + 64012288);      //  12,812,288
    int*            csr    = (int*)(ws + 76824576);               //  12,812,288
    int*            rowbeg = (int*)(ws + 89636864);               //     400,384
    int*            rowend = (int*)(ws + 90037248);               //     400,384
    int*            bcur   = (int*)(ws + 90437632);               //       3,136
    float*          g0     = (float*)(ws + 90440768);             //     131,072
    unsigned short* Bt1    = (unsigned short*)(ws + 90571840);    //      65,536
    float*          b1     = (float*)(ws + 90637376);             //       1,024
    unsigned short* Bt2    = (unsigned short*)(ws + 90638400);    //      32,768
    float*          b2     = (float*)(ws + 90671168);             //       1,024
    float*          bnp    = (float*)(ws + 90672192);             //       1,024

    const int* srcIdx = ei;
    const int* dstIdx = ei + EE;

    // Weight packing + BN scale/shift + g0/bcur zero (one dispatch)
    k_cvt_all<<<192, 256, 0, stream>>>(c1_wq, c1_bq, c1_wk, c1_bk, c1_wv, c1_bv,
                                       c1_ws, c1_bs,
                                       c2_wq, c2_bq, c2_wk, c2_bk, c2_wv, c2_bv,
                                       c2_ws, c2_bs,
                                       bn1_g, bn1_b, bn1_m, bn1_v,
                                       bn2_g, bn2_b, bn2_m, bn2_v,
                                       Bt1, b1, Bt2, b2, bnp, g0, bcur);

    // Fat kernel: edge partition (391 blocks) overlapped with conv1 gemm (782)
    k_gemm1_part<<<PBLK + GB1, 512, 0, stream>>>(x, Bt1, b1, kv, qsb,
                                                 srcIdx, dstIdx, bcur, ppair);

    // Per-bucket counting sort -> rowbeg/rowend/csr
    k_bucket<<<NBUCK, 512, 0, stream>>>(ppair, bcur, rowbeg, rowend, csr);

    // Conv1 attention
    attn_fused<<<NN / 4, 256, 0, stream>>>(qsb, (const unsigned char*)kv,
                                           rowbeg, rowend, csr,
                                           bnp, bnp + 64, (uint4*)hbuf);

    // Conv2
    k_gemm2<<<GB1, 512, 0, stream>>>(hbuf, Bt2, b2, kv, qsb);
    attn_fused<<<NN / 4, 256, 0, stream>>>(qsb, (const unsigned char*)kv,
                                           rowbeg, rowend, csr,
                                           bnp + 128, bnp + 192, (uint4*)hbuf);

    // Pool + MLP head
    k_pool<<<(NN + 255) / 256, 256, 0, stream>>>((const unsigned int*)hbuf, batch, g0);
    k_mlp<<<GG / 4, 256, 0, stream>>>(g0, p1_w, p1_b, p2_w, p2_b, cl1_w, cl1_b,
                                      clbn_g, clbn_b, clbn_m, clbn_v, cl2_w, cl2_b,
                                      (float*)d_out);
}